// Round 2
// baseline (6592.413 us; speedup 1.0000x reference)
//
#include <hip/hip_runtime.h>
#include <cmath>

#define B_   2048
#define S_   60
#define NTOK (B_*S_)
#define IND_ 211
#define D_   192
#define H_   6
#define DK_  32
#define L_   3
#define DFF_ 768
#define NC_  35
#define DH_  96

typedef unsigned short us_t;
typedef us_t us8 __attribute__((ext_vector_type(8)));
typedef us_t us4 __attribute__((ext_vector_type(4)));

__device__ __forceinline__ float bf2f(us_t u) {
    union { unsigned int i; float f; } v; v.i = ((unsigned int)u) << 16; return v.f;
}
__device__ __forceinline__ us_t f2bf(float f) {
    union { float f; unsigned int i; } v; v.f = f;
    unsigned int r = v.i + 0x7fffu + ((v.i >> 16) & 1u);
    return (us_t)(r >> 16);
}
__device__ __forceinline__ float gelu_f(float v) {
    return 0.5f * v * (1.0f + erff(v * 0.7071067811865475f));
}

// ---------------------------------------------------------------------------
// Tiled GEMM: 64 tokens x 192 cols per block, 256 threads, 4x12 micro-tile.
// EPI 0 = bias + pe -> bf16 out (input projection, A = f32 scalar path K=211)
// EPI 3 = bias + bf16-residual + LayerNorm -> bf16 out (A = bf16, K=192)
// ---------------------------------------------------------------------------
template<int KT, int EPI, bool ABF>
__global__ __launch_bounds__(256) void gemm_tile(
    const void* __restrict__ Ap, int lda,
    const float* __restrict__ W, int ldw,
    const float* __restrict__ bias,
    us_t* __restrict__ out, int ldo,
    const us_t* __restrict__ resid,
    const float* __restrict__ gamma, const float* __restrict__ beta,
    const float* __restrict__ pe)
{
    constexpr int BM = 64, BN = 192, BK = 32;
    constexpr int NCH = (KT + BK - 1) / BK;
    __shared__ __align__(16) float As[BK][68];
    __shared__ __align__(16) float Bs[BK][BN];

    const int tid = threadIdx.x;
    const int ty = tid >> 4, tx = tid & 15;
    const int row0 = blockIdx.x * BM;

    float acc[4][12];
    #pragma unroll
    for (int i = 0; i < 4; ++i)
        #pragma unroll
        for (int j = 0; j < 12; ++j) acc[i][j] = 0.f;

    for (int ch = 0; ch < NCH; ++ch) {
        const int k0 = ch * BK;
        __syncthreads();
        if (ABF) {
            const us_t* A = (const us_t*)Ap;
            int tok = tid >> 2, kv = tid & 3;   // 256 threads x 8 elems = 64x32
            us8 u = *(const us8*)&A[(size_t)(row0 + tok) * lda + k0 + kv * 8];
            #pragma unroll
            for (int j = 0; j < 8; ++j) As[kv * 8 + j][tok] = bf2f(u[j]);
        } else {
            const float* A = (const float*)Ap;
            #pragma unroll
            for (int p = 0; p < 8; ++p) {
                int e = tid + p * 256;
                int tok = e >> 5, kk = e & 31;
                int gk = k0 + kk;
                As[kk][tok] = (gk < KT) ? A[(size_t)(row0 + tok) * lda + gk] : 0.f;
            }
        }
        #pragma unroll
        for (int p = 0; p < 6; ++p) {
            int e = tid + p * 256;
            int r = e / 48, cv = e % 48;
            int gk = k0 + r;
            float4 wv;
            if (gk < KT) wv = *(const float4*)&W[(size_t)gk * ldw + cv * 4];
            else         wv = make_float4(0.f, 0.f, 0.f, 0.f);
            *(float4*)&Bs[r][cv * 4] = wv;
        }
        __syncthreads();
        #pragma unroll 4
        for (int k = 0; k < BK; ++k) {
            float4 af = *(const float4*)&As[k][ty * 4];
            float4 b0 = *(const float4*)&Bs[k][tx * 12];
            float4 b1 = *(const float4*)&Bs[k][tx * 12 + 4];
            float4 b2 = *(const float4*)&Bs[k][tx * 12 + 8];
            float av[4]  = {af.x, af.y, af.z, af.w};
            float bv[12] = {b0.x,b0.y,b0.z,b0.w, b1.x,b1.y,b1.z,b1.w, b2.x,b2.y,b2.z,b2.w};
            #pragma unroll
            for (int i = 0; i < 4; ++i)
                #pragma unroll
                for (int j = 0; j < 12; ++j)
                    acc[i][j] = fmaf(av[i], bv[j], acc[i][j]);
        }
    }

    const int cbase = tx * 12;
    #pragma unroll
    for (int i = 0; i < 4; ++i) {
        const int tok = row0 + ty * 4 + i;
        if (EPI == 0) {
            const int s = tok % S_;
            #pragma unroll
            for (int jv = 0; jv < 3; ++jv) {
                float4 bv = *(const float4*)&bias[cbase + jv * 4];
                float4 pv = *(const float4*)&pe[(size_t)s * D_ + cbase + jv * 4];
                us4 o4;
                o4[0] = f2bf(acc[i][jv*4+0] + bv.x + pv.x);
                o4[1] = f2bf(acc[i][jv*4+1] + bv.y + pv.y);
                o4[2] = f2bf(acc[i][jv*4+2] + bv.z + pv.z);
                o4[3] = f2bf(acc[i][jv*4+3] + bv.w + pv.w);
                *(us4*)&out[(size_t)tok * ldo + cbase + jv * 4] = o4;
            }
        } else {
            float vrow[12];
            float sum = 0.f, ssq = 0.f;
            #pragma unroll
            for (int jv = 0; jv < 3; ++jv) {
                float4 bv = *(const float4*)&bias[cbase + jv * 4];
                us4 rv = *(const us4*)&resid[(size_t)tok * ldo + cbase + jv * 4];
                float t0 = acc[i][jv*4+0] + bv.x + bf2f(rv[0]);
                float t1 = acc[i][jv*4+1] + bv.y + bf2f(rv[1]);
                float t2 = acc[i][jv*4+2] + bv.z + bf2f(rv[2]);
                float t3 = acc[i][jv*4+3] + bv.w + bf2f(rv[3]);
                vrow[jv*4+0] = t0; vrow[jv*4+1] = t1; vrow[jv*4+2] = t2; vrow[jv*4+3] = t3;
                sum += t0 + t1 + t2 + t3;
                ssq += t0*t0 + t1*t1 + t2*t2 + t3*t3;
            }
            #pragma unroll
            for (int m = 1; m < 16; m <<= 1) {
                sum += __shfl_xor(sum, m);
                ssq += __shfl_xor(ssq, m);
            }
            const float mean = sum * (1.f / D_);
            const float var  = ssq * (1.f / D_) - mean * mean;
            const float rstd = rsqrtf(var + 1e-5f);
            #pragma unroll
            for (int jv = 0; jv < 3; ++jv) {
                float4 gv  = *(const float4*)&gamma[cbase + jv * 4];
                float4 bev = *(const float4*)&beta[cbase + jv * 4];
                us4 o4;
                o4[0] = f2bf((vrow[jv*4+0] - mean) * rstd * gv.x + bev.x);
                o4[1] = f2bf((vrow[jv*4+1] - mean) * rstd * gv.y + bev.y);
                o4[2] = f2bf((vrow[jv*4+2] - mean) * rstd * gv.z + bev.z);
                o4[3] = f2bf((vrow[jv*4+3] - mean) * rstd * gv.w + bev.w);
                *(us4*)&out[(size_t)tok * ldo + cbase + jv * 4] = o4;
            }
        }
    }
}

// ---------------------------------------------------------------------------
// Fused QKV + attention: one block per batch. h bf16 -> ctx bf16.
// Per head: stage W slices f32 in LDS, gemm-tile micro-kernel for q|k|v,
// then scores/softmax/PV all in f32 LDS/registers.
// ---------------------------------------------------------------------------
__global__ __launch_bounds__(256) void qkv_attn(
    const us_t* __restrict__ h,
    const float* __restrict__ Wq, const float* __restrict__ Wk, const float* __restrict__ Wv,
    const float* __restrict__ bq, const float* __restrict__ bk, const float* __restrict__ bv,
    us_t* __restrict__ ctx)
{
    __shared__ us_t xsT[D_][64];                  // [k][tok] bf16   24,576 B
    __shared__ __align__(16) float Whs[D_][100];  // q|k|v cols      76,800 B
    __shared__ __align__(16) float qkv[S_][100];  //                 24,000 B
    __shared__ float Ps[S_][66];                  //                 15,840 B
    const int t = threadIdx.x;
    const int b = blockIdx.x;
    const size_t hb = (size_t)b * (S_ * D_);

    for (int e = t; e < S_ * 24; e += 256) {       // 1440 x us8
        int tok = e / 24, v = e % 24;
        us8 u = *(const us8*)&h[hb + (size_t)tok * D_ + v * 8];
        #pragma unroll
        for (int j = 0; j < 8; ++j) xsT[v * 8 + j][tok] = u[j];
    }

    const int ty = t >> 4;     // 0..15 (use 0..14)
    const int tx = t & 15;

    for (int hh = 0; hh < H_; ++hh) {
        __syncthreads();
        for (int e = t; e < 4608; e += 256) {      // 3 mats x 1536 float4
            int mat = e / 1536, rem = e % 1536, r = rem >> 3, cv = rem & 7;
            const float* Wsrc = (mat == 0) ? Wq : (mat == 1) ? Wk : Wv;
            float4 w = *(const float4*)&Wsrc[(size_t)r * D_ + hh * DK_ + cv * 4];
            *(float4*)&Whs[r][mat * 32 + cv * 4] = w;
        }
        __syncthreads();

        if (t < 240) {                              // 15 ty-groups x 16 tx
            float acc[4][6];
            #pragma unroll
            for (int i = 0; i < 4; ++i)
                #pragma unroll
                for (int j = 0; j < 6; ++j) acc[i][j] = 0.f;
            for (int k = 0; k < D_; ++k) {
                us4 au = *(const us4*)&xsT[k][ty * 4];
                float av[4];
                #pragma unroll
                for (int i = 0; i < 4; ++i) av[i] = bf2f(au[i]);
                const float* wr = &Whs[k][tx * 6];
                float2 w0 = *(const float2*)&wr[0];
                float2 w1 = *(const float2*)&wr[2];
                float2 w2 = *(const float2*)&wr[4];
                float bv6[6] = {w0.x, w0.y, w1.x, w1.y, w2.x, w2.y};
                #pragma unroll
                for (int i = 0; i < 4; ++i)
                    #pragma unroll
                    for (int j = 0; j < 6; ++j)
                        acc[i][j] = fmaf(av[i], bv6[j], acc[i][j]);
            }
            float ob[6];
            #pragma unroll
            for (int j = 0; j < 6; ++j) {
                int c = tx * 6 + j, mat = c >> 5, cc = c & 31;
                const float* bsrc = (mat == 0) ? bq : (mat == 1) ? bk : bv;
                ob[j] = bsrc[hh * DK_ + cc];
            }
            #pragma unroll
            for (int i = 0; i < 4; ++i) {
                int tok = ty * 4 + i;
                #pragma unroll
                for (int j = 0; j < 6; ++j)
                    qkv[tok][tx * 6 + j] = acc[i][j] + ob[j];
            }
        }
        __syncthreads();

        if (t < 240) {                              // scores + softmax: 4 lanes/query
            int tokq = t >> 2, kq = t & 3;
            float qreg[DK_];
            #pragma unroll
            for (int dv = 0; dv < 8; ++dv) {
                float4 qv = *(const float4*)&qkv[tokq][dv * 4];
                qreg[dv*4+0] = qv.x; qreg[dv*4+1] = qv.y;
                qreg[dv*4+2] = qv.z; qreg[dv*4+3] = qv.w;
            }
            float sc[15];
            #pragma unroll
            for (int j = 0; j < 15; ++j) {
                int key = kq * 15 + j;
                float dot = 0.f;
                #pragma unroll
                for (int dv = 0; dv < 8; ++dv) {
                    float4 kv4 = *(const float4*)&qkv[key][32 + dv * 4];
                    dot = fmaf(qreg[dv*4+0], kv4.x, dot);
                    dot = fmaf(qreg[dv*4+1], kv4.y, dot);
                    dot = fmaf(qreg[dv*4+2], kv4.z, dot);
                    dot = fmaf(qreg[dv*4+3], kv4.w, dot);
                }
                sc[j] = dot * 0.17677669529663687f;
            }
            float m = sc[0];
            #pragma unroll
            for (int j = 1; j < 15; ++j) m = fmaxf(m, sc[j]);
            m = fmaxf(m, __shfl_xor(m, 1));
            m = fmaxf(m, __shfl_xor(m, 2));
            float s = 0.f;
            #pragma unroll
            for (int j = 0; j < 15; ++j) { sc[j] = __expf(sc[j] - m); s += sc[j]; }
            s += __shfl_xor(s, 1);
            s += __shfl_xor(s, 2);
            float inv = 1.f / s;
            #pragma unroll
            for (int j = 0; j < 15; ++j) Ps[tokq][kq * 15 + j] = sc[j] * inv;
        }
        __syncthreads();

        if (t < 240) {                              // PV: 4 lanes/query, 8 d-cols each
            int tokq = t >> 2, q4 = t & 3;
            float acc[8];
            #pragma unroll
            for (int d = 0; d < 8; ++d) acc[d] = 0.f;
            for (int key = 0; key < S_; ++key) {
                float p = Ps[tokq][key];
                float4 v0 = *(const float4*)&qkv[key][64 + q4 * 8];
                float4 v1 = *(const float4*)&qkv[key][64 + q4 * 8 + 4];
                acc[0] = fmaf(p, v0.x, acc[0]); acc[1] = fmaf(p, v0.y, acc[1]);
                acc[2] = fmaf(p, v0.z, acc[2]); acc[3] = fmaf(p, v0.w, acc[3]);
                acc[4] = fmaf(p, v1.x, acc[4]); acc[5] = fmaf(p, v1.y, acc[5]);
                acc[6] = fmaf(p, v1.z, acc[6]); acc[7] = fmaf(p, v1.w, acc[7]);
            }
            us8 o;
            #pragma unroll
            for (int d = 0; d < 8; ++d) o[d] = f2bf(acc[d]);
            *(us8*)&ctx[hb + (size_t)tokq * D_ + hh * DK_ + q4 * 8] = o;
        }
    }
}

// ---------------------------------------------------------------------------
// Fused FF: gelu(x@W1+b1)@W2+b2 + residual + LN, chunked over DFF (4 x 192).
// LDS 79.9 KB -> 2 blocks/CU. h updated in place (bf16).
// ---------------------------------------------------------------------------
__global__ __launch_bounds__(256) void fused_ff(
    us_t* __restrict__ hio,
    const float* __restrict__ W1, const float* __restrict__ b1,
    const float* __restrict__ W2, const float* __restrict__ b2,
    const float* __restrict__ gamma, const float* __restrict__ beta)
{
    __shared__ us_t xsT[D_][72];                 // [col][tok]  27,648 B
    __shared__ us_t tsT[D_][72];                 // gelu chunk  27,648 B
    __shared__ __align__(16) float Bs[32][D_];   //             24,576 B
    const int tid = threadIdx.x;
    const int ty = tid >> 4, tx = tid & 15;
    const int row0 = blockIdx.x * 64;

    for (int e = tid; e < 1536; e += 256) {
        int tok = e / 24, v = e % 24;
        us8 u = *(const us8*)&hio[(size_t)(row0 + tok) * D_ + v * 8];
        #pragma unroll
        for (int j = 0; j < 8; ++j) xsT[v * 8 + j][tok] = u[j];
    }

    float acc2[4][12];
    #pragma unroll
    for (int i = 0; i < 4; ++i)
        #pragma unroll
        for (int j = 0; j < 12; ++j) acc2[i][j] = 0.f;

    for (int c = 0; c < 4; ++c) {
        float acc1[4][12];
        #pragma unroll
        for (int i = 0; i < 4; ++i)
            #pragma unroll
            for (int j = 0; j < 12; ++j) acc1[i][j] = 0.f;

        for (int kc = 0; kc < 6; ++kc) {          // FF1: K = 192
            __syncthreads();
            #pragma unroll
            for (int p = 0; p < 6; ++p) {
                int e = tid + p * 256, r = e / 48, cv = e % 48;
                *(float4*)&Bs[r][cv * 4] =
                    *(const float4*)&W1[(size_t)(kc * 32 + r) * DFF_ + c * D_ + cv * 4];
            }
            __syncthreads();
            #pragma unroll 4
            for (int k = 0; k < 32; ++k) {
                us4 au = *(const us4*)&xsT[kc * 32 + k][ty * 4];
                float av[4];
                #pragma unroll
                for (int i = 0; i < 4; ++i) av[i] = bf2f(au[i]);
                float4 b0 = *(const float4*)&Bs[k][tx * 12];
                float4 b1v = *(const float4*)&Bs[k][tx * 12 + 4];
                float4 b2v = *(const float4*)&Bs[k][tx * 12 + 8];
                float bv[12] = {b0.x,b0.y,b0.z,b0.w, b1v.x,b1v.y,b1v.z,b1v.w,
                                b2v.x,b2v.y,b2v.z,b2v.w};
                #pragma unroll
                for (int i = 0; i < 4; ++i)
                    #pragma unroll
                    for (int j = 0; j < 12; ++j)
                        acc1[i][j] = fmaf(av[i], bv[j], acc1[i][j]);
            }
        }
        // gelu + bias -> tsT (ordering vs other waves is guaranteed by the
        // barriers inside the kc loops: prev-chunk readers passed FF1 kc=0's
        // barrier; FF2 kc=0's barrier precedes any read of these writes)
        #pragma unroll
        for (int i = 0; i < 4; ++i)
            #pragma unroll
            for (int j = 0; j < 12; ++j) {
                float vv = acc1[i][j] + b1[c * D_ + tx * 12 + j];
                tsT[tx * 12 + j][ty * 4 + i] = f2bf(gelu_f(vv));
            }

        for (int kc = 0; kc < 6; ++kc) {          // FF2 partial: K = 192 chunk
            __syncthreads();
            #pragma unroll
            for (int p = 0; p < 6; ++p) {
                int e = tid + p * 256, r = e / 48, cv = e % 48;
                *(float4*)&Bs[r][cv * 4] =
                    *(const float4*)&W2[(size_t)(c * D_ + kc * 32 + r) * D_ + cv * 4];
            }
            __syncthreads();
            #pragma unroll 4
            for (int k = 0; k < 32; ++k) {
                us4 au = *(const us4*)&tsT[kc * 32 + k][ty * 4];
                float av[4];
                #pragma unroll
                for (int i = 0; i < 4; ++i) av[i] = bf2f(au[i]);
                float4 b0 = *(const float4*)&Bs[k][tx * 12];
                float4 b1v = *(const float4*)&Bs[k][tx * 12 + 4];
                float4 b2v = *(const float4*)&Bs[k][tx * 12 + 8];
                float bv[12] = {b0.x,b0.y,b0.z,b0.w, b1v.x,b1v.y,b1v.z,b1v.w,
                                b2v.x,b2v.y,b2v.z,b2v.w};
                #pragma unroll
                for (int i = 0; i < 4; ++i)
                    #pragma unroll
                    for (int j = 0; j < 12; ++j)
                        acc2[i][j] = fmaf(av[i], bv[j], acc2[i][j]);
            }
        }
    }

    const int cbase = tx * 12;
    #pragma unroll
    for (int i = 0; i < 4; ++i) {
        const int tok = row0 + ty * 4 + i;
        float vrow[12], sum = 0.f, ssq = 0.f;
        #pragma unroll
        for (int j = 0; j < 12; ++j) {
            float r = bf2f(xsT[cbase + j][ty * 4 + i]);
            float vv = acc2[i][j] + b2[cbase + j] + r;
            vrow[j] = vv; sum += vv; ssq += vv * vv;
        }
        #pragma unroll
        for (int m = 1; m < 16; m <<= 1) {
            sum += __shfl_xor(sum, m);
            ssq += __shfl_xor(ssq, m);
        }
        const float mean = sum * (1.f / D_);
        const float var  = ssq * (1.f / D_) - mean * mean;
        const float rstd = rsqrtf(var + 1e-5f);
        us_t ob[12];
        #pragma unroll
        for (int j = 0; j < 12; ++j)
            ob[j] = f2bf((vrow[j] - mean) * rstd * gamma[cbase + j] + beta[cbase + j]);
        #pragma unroll
        for (int jq = 0; jq < 3; ++jq) {
            us4 o4 = {ob[jq*4], ob[jq*4+1], ob[jq*4+2], ob[jq*4+3]};
            *(us4*)&hio[(size_t)tok * D_ + cbase + jq * 4] = o4;
        }
    }
}

// ---------------------------------------------------------------------------
// Classifier stage 1: hid = gelu(h @ Wc1 + bc1)  (h bf16 -> hid f32)
// ---------------------------------------------------------------------------
__global__ __launch_bounds__(256) void clf1_kernel(
    const us_t* __restrict__ h, const float* __restrict__ Wc1,
    const float* __restrict__ bc1, float* __restrict__ hid)
{
    __shared__ us_t Hs[64][200];
    const int tid = threadIdx.x;
    const int row0 = blockIdx.x * 64;
    for (int e = tid; e < 1536; e += 256) {
        int tok = e / 24, v = e % 24;
        us8 u = *(const us8*)&h[(size_t)(row0 + tok) * D_ + v * 8];
        *(us8*)&Hs[tok][v * 8] = u;
    }
    __syncthreads();
    const int tok = tid >> 2;
    const int c0 = (tid & 3) * 24;
    float acc[24];
    #pragma unroll
    for (int j = 0; j < 24; ++j) acc[j] = 0.f;
    #pragma unroll 4
    for (int kk = 0; kk < D_; ++kk) {
        const float hv = bf2f(Hs[tok][kk]);
        const float* wr = &Wc1[(size_t)kk * DH_ + c0];
        #pragma unroll
        for (int jv = 0; jv < 6; ++jv) {
            float4 w = *(const float4*)&wr[jv * 4];
            acc[jv*4+0] = fmaf(hv, w.x, acc[jv*4+0]);
            acc[jv*4+1] = fmaf(hv, w.y, acc[jv*4+1]);
            acc[jv*4+2] = fmaf(hv, w.z, acc[jv*4+2]);
            acc[jv*4+3] = fmaf(hv, w.w, acc[jv*4+3]);
        }
    }
    #pragma unroll
    for (int jv = 0; jv < 6; ++jv) {
        float4 bv = *(const float4*)&bc1[c0 + jv * 4];
        float4 o;
        o.x = gelu_f(acc[jv*4+0] + bv.x);
        o.y = gelu_f(acc[jv*4+1] + bv.y);
        o.z = gelu_f(acc[jv*4+2] + bv.z);
        o.w = gelu_f(acc[jv*4+3] + bv.w);
        *(float4*)&hid[(size_t)(row0 + tok) * DH_ + c0 + jv * 4] = o;
    }
}

// ---------------------------------------------------------------------------
// Classifier stage 2: out = hid @ Wc2 + bc2  (f32)
// ---------------------------------------------------------------------------
__global__ __launch_bounds__(256) void clf2_kernel(
    const float* __restrict__ hid, const float* __restrict__ Wc2,
    const float* __restrict__ bc2, float* __restrict__ out)
{
    __shared__ __align__(16) float Hs[64][100];
    __shared__ float Wl[DH_ * NC_];
    __shared__ float bl[NC_];
    const int tid = threadIdx.x;
    const int row0 = blockIdx.x * 64;
    #pragma unroll
    for (int p = 0; p < 6; ++p) {
        int e = tid + p * 256;
        int tok = e / 24, cv = e % 24;
        *(float4*)&Hs[tok][cv * 4] = *(const float4*)&hid[(size_t)(row0 + tok) * DH_ + cv * 4];
    }
    for (int e = tid; e < DH_ * NC_; e += 256) Wl[e] = Wc2[e];
    if (tid < NC_) bl[tid] = bc2[tid];
    __syncthreads();
    for (int e = tid; e < 64 * NC_; e += 256) {
        const int tok = e / NC_, col = e % NC_;
        float acc = bl[col];
        #pragma unroll 8
        for (int kk = 0; kk < DH_; ++kk)
            acc = fmaf(Hs[tok][kk], Wl[kk * NC_ + col], acc);
        out[(size_t)(row0 + tok) * NC_ + col] = acc;
    }
}

extern "C" void kernel_launch(void* const* d_in, const int* in_sizes, int n_in,
                              void* d_out, int out_size, void* d_ws, size_t ws_size,
                              hipStream_t stream)
{
    const float* x    = (const float*)d_in[0];
    const float* W_in = (const float*)d_in[1];
    const float* b_in = (const float*)d_in[2];
    const float* pe   = (const float*)d_in[3];
    const float* Wq   = (const float*)d_in[4];
    const float* bq   = (const float*)d_in[5];
    const float* Wk   = (const float*)d_in[6];
    const float* bk   = (const float*)d_in[7];
    const float* Wv   = (const float*)d_in[8];
    const float* bv   = (const float*)d_in[9];
    const float* Wo   = (const float*)d_in[10];
    const float* bo   = (const float*)d_in[11];
    const float* W1   = (const float*)d_in[12];
    const float* b1   = (const float*)d_in[13];
    const float* W2   = (const float*)d_in[14];
    const float* b2   = (const float*)d_in[15];
    const float* g1   = (const float*)d_in[16];
    const float* be1  = (const float*)d_in[17];
    const float* g2   = (const float*)d_in[18];
    const float* be2  = (const float*)d_in[19];
    const float* Wc1  = (const float*)d_in[20];
    const float* bc1  = (const float*)d_in[21];
    const float* Wc2  = (const float*)d_in[22];
    const float* bc2  = (const float*)d_in[23];
    float* outp = (float*)d_out;

    // workspace: h bf16 [N,192] (47.2 MB) | r2 (47.2 MB: ctx bf16, later hid f32)
    us_t* h   = (us_t*)d_ws;
    char* r2  = (char*)d_ws + (size_t)NTOK * D_ * 2;
    us_t*  ctx = (us_t*)r2;
    float* hid = (float*)r2;

    const dim3 blk(256);
    const int gx = NTOK / 64;   // 1920

    gemm_tile<IND_, 0, false><<<gx, blk, 0, stream>>>(
        x, IND_, W_in, D_, b_in, h, D_, nullptr, nullptr, nullptr, pe);

    for (int l = 0; l < L_; ++l) {
        qkv_attn<<<B_, blk, 0, stream>>>(
            h,
            Wq + (size_t)l * D_ * D_, Wk + (size_t)l * D_ * D_, Wv + (size_t)l * D_ * D_,
            bq + l * D_, bk + l * D_, bv + l * D_, ctx);

        gemm_tile<D_, 3, true><<<gx, blk, 0, stream>>>(
            ctx, D_, Wo + (size_t)l * D_ * D_, D_, bo + l * D_, h, D_,
            h, g1 + l * D_, be1 + l * D_, nullptr);

        fused_ff<<<gx, blk, 0, stream>>>(
            h, W1 + (size_t)l * D_ * DFF_, b1 + l * DFF_,
            W2 + (size_t)l * DFF_ * D_, b2 + l * D_,
            g2 + l * D_, be2 + l * D_);
    }

    clf1_kernel<<<gx, blk, 0, stream>>>(h, Wc1, bc1, hid);
    clf2_kernel<<<gx, blk, 0, stream>>>(hid, Wc2, bc2, outp);
}

// Round 4
// 1514.061 us; speedup vs baseline: 4.3541x; 4.3541x over previous
//
#include <hip/hip_runtime.h>
#include <cmath>

#define B_   2048
#define S_   60
#define NTOK (B_*S_)
#define IND_ 211
#define D_   192
#define H_   6
#define DK_  32
#define L_   3
#define DFF_ 768
#define NC_  35
#define DH_  96

typedef unsigned short us_t;
typedef us_t us8 __attribute__((ext_vector_type(8)));
typedef us_t us4 __attribute__((ext_vector_type(4)));
typedef short sh8 __attribute__((ext_vector_type(8)));
typedef float f4 __attribute__((ext_vector_type(4)));

#define MFMA(a, b, cc) __builtin_amdgcn_mfma_f32_16x16x32_bf16((a), (b), (cc), 0, 0, 0)
#define ZACC(A, M, N) \
    for (int _i = 0; _i < (M); ++_i) \
        for (int _j = 0; _j < (N); ++_j) { \
            A[_i][_j][0] = 0.f; A[_i][_j][1] = 0.f; A[_i][_j][2] = 0.f; A[_i][_j][3] = 0.f; }
#define ZACC1(A, N) \
    for (int _j = 0; _j < (N); ++_j) { \
        A[_j][0] = 0.f; A[_j][1] = 0.f; A[_j][2] = 0.f; A[_j][3] = 0.f; }

__device__ __forceinline__ float bf2f(us_t u) {
    union { unsigned int i; float f; } v; v.i = ((unsigned int)u) << 16; return v.f;
}
__device__ __forceinline__ us_t f2bf(float f) {
    union { float f; unsigned int i; } v; v.f = f;
    unsigned int r = v.i + 0x7fffu + ((v.i >> 16) & 1u);
    return (us_t)(r >> 16);
}
__device__ __forceinline__ float gelu_f(float v) {
    return 0.5f * v * (1.0f + erff(v * 0.7071067811865475f));
}

// ---------------------------------------------------------------------------
// Weight prep: out[n][kp] = bf16(in[kp][n]), zero-padded to Kpad.
// ---------------------------------------------------------------------------
__global__ void prep_t(const float* __restrict__ in, us_t* __restrict__ out,
                       int K, int Kpad, int N)
{
    int e = blockIdx.x * 256 + threadIdx.x;
    if (e >= N * Kpad) return;
    int n = e / Kpad, kp = e % Kpad;
    out[e] = (kp < K) ? f2bf(in[(size_t)kp * N + n]) : (us_t)0;
}

// ---------------------------------------------------------------------------
// Input projection: h = bf16(x @ W_in + b_in + pe). 64 tok/block, 4 waves.
// ---------------------------------------------------------------------------
__global__ __launch_bounds__(256) void inp_mfma(
    const float* __restrict__ x, const us_t* __restrict__ Wint,
    const float* __restrict__ b_in, const float* __restrict__ pe,
    us_t* __restrict__ h)
{
    __shared__ __align__(16) char smem[29696 + 27648];
    us_t* Xs = (us_t*)smem;              // [64][232]
    us_t* Ws = (us_t*)(smem + 29696);    // [192][72]
    const int tid = threadIdx.x;
    const int lane = tid & 63, wid = tid >> 6;
    const int g = lane >> 4, c = lane & 15;
    const int wr = wid >> 1, wc = wid & 1;
    const int row0 = blockIdx.x * 64;

    for (int e = tid; e < 64 * 224; e += 256) {
        int tok = e / 224, kp = e % 224;
        float v = (kp < IND_) ? x[(size_t)(row0 + tok) * IND_ + kp] : 0.f;
        Xs[tok * 232 + kp] = f2bf(v);
    }

    f4 acc[2][6];
    ZACC(acc, 2, 6);
    for (int pc = 0; pc < 4; ++pc) {
        __syncthreads();
        const int nk = (pc < 3) ? 64 : 32;
        const int per = nk / 8;
        for (int e = tid; e < 192 * per; e += 256) {
            int rw = e / per, v = e % per;
            *(us8*)&Ws[rw * 72 + v * 8] =
                *(const us8*)&Wint[(size_t)rw * 224 + pc * 64 + v * 8];
        }
        __syncthreads();
        for (int kk = 0; kk < nk / 32; ++kk) {
            const int ka = pc * 64 + kk * 32 + g * 8;
            const int kw = kk * 32 + g * 8;
            sh8 a0 = *(const sh8*)&Xs[(32 * wr + c) * 232 + ka];
            sh8 a1 = *(const sh8*)&Xs[(32 * wr + 16 + c) * 232 + ka];
            #pragma unroll
            for (int ni = 0; ni < 6; ++ni) {
                sh8 bf = *(const sh8*)&Ws[(96 * wc + 16 * ni + c) * 72 + kw];
                acc[0][ni] = MFMA(a0, bf, acc[0][ni]);
                acc[1][ni] = MFMA(a1, bf, acc[1][ni]);
            }
        }
    }
    #pragma unroll
    for (int ni = 0; ni < 6; ++ni) {
        const int col = 96 * wc + 16 * ni + c;
        const float bv = b_in[col];
        #pragma unroll
        for (int mi = 0; mi < 2; ++mi)
            #pragma unroll
            for (int r = 0; r < 4; ++r) {
                int tokg = row0 + 32 * wr + 16 * mi + 4 * g + r;
                int s = tokg % S_;
                float val = acc[mi][ni][r] + bv + pe[(size_t)s * D_ + col];
                h[(size_t)tokg * D_ + col] = f2bf(val);
            }
    }
}

// ---------------------------------------------------------------------------
// Fused QKV + attention + Wo + residual + LN. One 512-thread block per batch.
// ---------------------------------------------------------------------------
__global__ __launch_bounds__(512) void qkv_attn_wo(
    us_t* __restrict__ h,
    const us_t* __restrict__ Wqt, const us_t* __restrict__ Wkt,
    const us_t* __restrict__ Wvt, const us_t* __restrict__ Wot,
    const float* __restrict__ bq, const float* __restrict__ bk,
    const float* __restrict__ bv, const float* __restrict__ bo,
    const float* __restrict__ g1, const float* __restrict__ be1)
{
    __shared__ __align__(16) char smem[157696];
    us_t* Xs = (us_t*)smem;               // [64][200]
    us_t* Qs = (us_t*)(smem + 25600);     // [64][200]
    us_t* Ks = (us_t*)(smem + 51200);     // [64][200]
    us_t* Vt = (us_t*)(smem + 76800);     // [192][72] (V transposed: [col][tok])
    us_t* Ws = (us_t*)(smem + 104448);    // [192][72]
    us_t* P0 = (us_t*)(smem + 104448);    // [64][72]  overlays Ws
    us_t* P1 = (us_t*)(smem + 113664);    // [64][72]
    us_t* Cx = (us_t*)(smem + 132096);    // [64][200]
    float* eL = (float*)(smem + 51200);   // [64][200] f32, overlays Ks+Vt

    const int tid = threadIdx.x;
    const int lane = tid & 63, wid = tid >> 6;
    const int g = lane >> 4, c = lane & 15;
    const int wr = wid >> 2, wc = wid & 3;
    us_t* hb = h + (size_t)blockIdx.x * (S_ * D_);

    // stage X (rows 60..63 zero)
    for (int e = tid; e < 1536; e += 512) {
        int tok = e / 24, v = e % 24;
        us8 u = {0, 0, 0, 0, 0, 0, 0, 0};
        if (tok < S_) u = *(const us8*)&hb[(size_t)tok * D_ + v * 8];
        *(us8*)&Xs[tok * 200 + v * 8] = u;
    }

    // ---- QKV projections ----
    for (int m = 0; m < 3; ++m) {
        const us_t* Wt = (m == 0) ? Wqt : (m == 1) ? Wkt : Wvt;
        const float* bb = (m == 0) ? bq : (m == 1) ? bk : bv;
        f4 acc[2][3];
        ZACC(acc, 2, 3);
        for (int pc = 0; pc < 3; ++pc) {
            __syncthreads();
            for (int e = tid; e < 1536; e += 512) {
                int rw = e >> 3, v = e & 7;
                *(us8*)&Ws[rw * 72 + v * 8] =
                    *(const us8*)&Wt[(size_t)rw * 192 + pc * 64 + v * 8];
            }
            __syncthreads();
            #pragma unroll
            for (int kk = 0; kk < 2; ++kk) {
                const int ka = pc * 64 + kk * 32 + g * 8;
                const int kw = kk * 32 + g * 8;
                sh8 a0 = *(const sh8*)&Xs[(32 * wr + c) * 200 + ka];
                sh8 a1 = *(const sh8*)&Xs[(32 * wr + 16 + c) * 200 + ka];
                #pragma unroll
                for (int ni = 0; ni < 3; ++ni) {
                    sh8 bf = *(const sh8*)&Ws[(48 * wc + 16 * ni + c) * 72 + kw];
                    acc[0][ni] = MFMA(a0, bf, acc[0][ni]);
                    acc[1][ni] = MFMA(a1, bf, acc[1][ni]);
                }
            }
        }
        #pragma unroll
        for (int ni = 0; ni < 3; ++ni) {
            const int col = 48 * wc + 16 * ni + c;
            const float bval = bb[col];
            #pragma unroll
            for (int mi = 0; mi < 2; ++mi)
                #pragma unroll
                for (int r = 0; r < 4; ++r) {
                    int tok = 32 * wr + 16 * mi + 4 * g + r;
                    us_t o = f2bf(acc[mi][ni][r] + bval);
                    if (m == 0)      Qs[tok * 200 + col] = o;
                    else if (m == 1) Ks[tok * 200 + col] = o;
                    else             Vt[col * 72 + tok] = o;
                }
        }
    }
    __syncthreads();

    // ---- attention: 3 rounds x 2 heads; 4 waves (rowblocks) per head ----
    const int hgrp = wid & 3;     // q rowblock
    const int hsel = wid >> 2;    // head parity
    for (int rr = 0; rr < 3; ++rr) {
        const int hh = 2 * rr + hsel;
        us_t* Pb = hsel ? P1 : P0;
        f4 sc[4];
        ZACC1(sc, 4);
        {
            const int ka = 32 * hh + g * 8;
            sh8 aq = *(const sh8*)&Qs[(16 * hgrp + c) * 200 + ka];
            #pragma unroll
            for (int ni = 0; ni < 4; ++ni) {
                sh8 bk8 = *(const sh8*)&Ks[(16 * ni + c) * 200 + ka];
                sc[ni] = MFMA(aq, bk8, sc[ni]);
            }
        }
        #pragma unroll
        for (int r = 0; r < 4; ++r) {
            float mx = -1e30f;
            #pragma unroll
            for (int ni = 0; ni < 4; ++ni) {
                float v = sc[ni][r] * 0.17677669529663687f;
                if (16 * ni + c >= S_) v = -1e30f;
                sc[ni][r] = v;
                mx = fmaxf(mx, v);
            }
            mx = fmaxf(mx, __shfl_xor(mx, 1));
            mx = fmaxf(mx, __shfl_xor(mx, 2));
            mx = fmaxf(mx, __shfl_xor(mx, 4));
            mx = fmaxf(mx, __shfl_xor(mx, 8));
            float sum = 0.f;
            #pragma unroll
            for (int ni = 0; ni < 4; ++ni) {
                float e = __expf(sc[ni][r] - mx);
                sc[ni][r] = e; sum += e;
            }
            sum += __shfl_xor(sum, 1);
            sum += __shfl_xor(sum, 2);
            sum += __shfl_xor(sum, 4);
            sum += __shfl_xor(sum, 8);
            const float inv = 1.f / sum;
            #pragma unroll
            for (int ni = 0; ni < 4; ++ni)
                Pb[(16 * hgrp + 4 * g + r) * 72 + 16 * ni + c] = f2bf(sc[ni][r] * inv);
        }
        __syncthreads();
        f4 ov[2];
        ZACC1(ov, 2);
        #pragma unroll
        for (int kk = 0; kk < 2; ++kk) {
            sh8 ap = *(const sh8*)&Pb[(16 * hgrp + c) * 72 + kk * 32 + g * 8];
            #pragma unroll
            for (int n2 = 0; n2 < 2; ++n2) {
                sh8 bv8 = *(const sh8*)&Vt[(32 * hh + 16 * n2 + c) * 72 + kk * 32 + g * 8];
                ov[n2] = MFMA(ap, bv8, ov[n2]);
            }
        }
        #pragma unroll
        for (int n2 = 0; n2 < 2; ++n2)
            #pragma unroll
            for (int r = 0; r < 4; ++r)
                Cx[(16 * hgrp + 4 * g + r) * 200 + 32 * hh + 16 * n2 + c] = f2bf(ov[n2][r]);
        __syncthreads();
    }

    // ---- Wo projection ----
    f4 aw[2][3];
    ZACC(aw, 2, 3);
    for (int pc = 0; pc < 3; ++pc) {
        __syncthreads();
        for (int e = tid; e < 1536; e += 512) {
            int rw = e >> 3, v = e & 7;
            *(us8*)&Ws[rw * 72 + v * 8] =
                *(const us8*)&Wot[(size_t)rw * 192 + pc * 64 + v * 8];
        }
        __syncthreads();
        #pragma unroll
        for (int kk = 0; kk < 2; ++kk) {
            const int ka = pc * 64 + kk * 32 + g * 8;
            const int kw = kk * 32 + g * 8;
            sh8 a0 = *(const sh8*)&Cx[(32 * wr + c) * 200 + ka];
            sh8 a1 = *(const sh8*)&Cx[(32 * wr + 16 + c) * 200 + ka];
            #pragma unroll
            for (int ni = 0; ni < 3; ++ni) {
                sh8 bf = *(const sh8*)&Ws[(48 * wc + 16 * ni + c) * 72 + kw];
                aw[0][ni] = MFMA(a0, bf, aw[0][ni]);
                aw[1][ni] = MFMA(a1, bf, aw[1][ni]);
            }
        }
    }
    __syncthreads();
    #pragma unroll
    for (int ni = 0; ni < 3; ++ni) {
        const int col = 48 * wc + 16 * ni + c;
        const float bov = bo[col];
        #pragma unroll
        for (int mi = 0; mi < 2; ++mi)
            #pragma unroll
            for (int r = 0; r < 4; ++r) {
                int tok = 32 * wr + 16 * mi + 4 * g + r;
                eL[tok * 200 + col] = aw[mi][ni][r] + bov + bf2f(Xs[tok * 200 + col]);
            }
    }
    __syncthreads();
    {
        const int tok = tid >> 3, t8 = tid & 7;
        float vals[24], sum = 0.f, ssq = 0.f;
        #pragma unroll
        for (int jv = 0; jv < 6; ++jv) {
            float4 v4 = *(const float4*)&eL[tok * 200 + t8 * 24 + jv * 4];
            vals[jv*4+0] = v4.x; vals[jv*4+1] = v4.y; vals[jv*4+2] = v4.z; vals[jv*4+3] = v4.w;
            sum += v4.x + v4.y + v4.z + v4.w;
            ssq += v4.x*v4.x + v4.y*v4.y + v4.z*v4.z + v4.w*v4.w;
        }
        sum += __shfl_xor(sum, 1); sum += __shfl_xor(sum, 2); sum += __shfl_xor(sum, 4);
        ssq += __shfl_xor(ssq, 1); ssq += __shfl_xor(ssq, 2); ssq += __shfl_xor(ssq, 4);
        const float mean = sum * (1.f / D_);
        const float var  = ssq * (1.f / D_) - mean * mean;
        const float rstd = rsqrtf(var + 1e-5f);
        if (tok < S_) {
            #pragma unroll
            for (int jv = 0; jv < 6; ++jv) {
                us4 o4;
                #pragma unroll
                for (int j = 0; j < 4; ++j) {
                    int col = t8 * 24 + jv * 4 + j;
                    o4[j] = f2bf((vals[jv*4+j] - mean) * rstd * g1[col] + be1[col]);
                }
                *(us4*)&hb[(size_t)tok * D_ + t8 * 24 + jv * 4] = o4;
            }
        }
    }
}

// ---------------------------------------------------------------------------
// Fused FF: gelu(x@W1+b1)@W2+b2 + residual + LN. 128 tok/block, 8 waves.
// ---------------------------------------------------------------------------
__global__ __launch_bounds__(512) void ff_mfma(
    us_t* __restrict__ hio,
    const us_t* __restrict__ W1t, const float* __restrict__ b1,
    const us_t* __restrict__ W2t, const float* __restrict__ b2,
    const float* __restrict__ gamma, const float* __restrict__ beta)
{
    __shared__ __align__(16) char smem[130048];
    us_t* Xs = (us_t*)smem;               // [128][200]
    us_t* Ts = (us_t*)(smem + 51200);     // [128][200]
    us_t* Ws = (us_t*)(smem + 102400);    // [192][72]
    float* eL = (float*)(smem + 51200);   // [64][200] f32, overlays Ts

    const int tid = threadIdx.x;
    const int lane = tid & 63, wid = tid >> 6;
    const int g = lane >> 4, c = lane & 15;
    const int wr = wid >> 1, wc = wid & 1;
    const int row0 = blockIdx.x * 128;

    for (int e = tid; e < 3072; e += 512) {
        int tok = e / 24, v = e % 24;
        *(us8*)&Xs[tok * 200 + v * 8] = *(const us8*)&hio[(size_t)(row0 + tok) * D_ + v * 8];
    }

    f4 acc2[2][6];
    ZACC(acc2, 2, 6);
    for (int cb = 0; cb < 4; ++cb) {
        f4 acc1[2][6];
        ZACC(acc1, 2, 6);
        for (int pc = 0; pc < 3; ++pc) {
            __syncthreads();
            for (int e = tid; e < 1536; e += 512) {
                int rw = e >> 3, v = e & 7;
                *(us8*)&Ws[rw * 72 + v * 8] =
                    *(const us8*)&W1t[(size_t)(cb * 192 + rw) * 192 + pc * 64 + v * 8];
            }
            __syncthreads();
            #pragma unroll
            for (int kk = 0; kk < 2; ++kk) {
                const int ka = pc * 64 + kk * 32 + g * 8;
                const int kw = kk * 32 + g * 8;
                sh8 a0 = *(const sh8*)&Xs[(32 * wr + c) * 200 + ka];
                sh8 a1 = *(const sh8*)&Xs[(32 * wr + 16 + c) * 200 + ka];
                #pragma unroll
                for (int ni = 0; ni < 6; ++ni) {
                    sh8 bf = *(const sh8*)&Ws[(96 * wc + 16 * ni + c) * 72 + kw];
                    acc1[0][ni] = MFMA(a0, bf, acc1[0][ni]);
                    acc1[1][ni] = MFMA(a1, bf, acc1[1][ni]);
                }
            }
        }
        #pragma unroll
        for (int ni = 0; ni < 6; ++ni) {
            const int col = 96 * wc + 16 * ni + c;
            const float b1v = b1[cb * 192 + col];
            #pragma unroll
            for (int mi = 0; mi < 2; ++mi)
                #pragma unroll
                for (int r = 0; r < 4; ++r) {
                    int tok = 32 * wr + 16 * mi + 4 * g + r;
                    Ts[tok * 200 + col] = f2bf(gelu_f(acc1[mi][ni][r] + b1v));
                }
        }
        for (int pc = 0; pc < 3; ++pc) {
            __syncthreads();
            for (int e = tid; e < 1536; e += 512) {
                int rw = e >> 3, v = e & 7;
                *(us8*)&Ws[rw * 72 + v * 8] =
                    *(const us8*)&W2t[(size_t)rw * 768 + cb * 192 + pc * 64 + v * 8];
            }
            __syncthreads();
            #pragma unroll
            for (int kk = 0; kk < 2; ++kk) {
                const int ka = pc * 64 + kk * 32 + g * 8;
                const int kw = kk * 32 + g * 8;
                sh8 a0 = *(const sh8*)&Ts[(32 * wr + c) * 200 + ka];
                sh8 a1 = *(const sh8*)&Ts[(32 * wr + 16 + c) * 200 + ka];
                #pragma unroll
                for (int ni = 0; ni < 6; ++ni) {
                    sh8 bf = *(const sh8*)&Ws[(96 * wc + 16 * ni + c) * 72 + kw];
                    acc2[0][ni] = MFMA(a0, bf, acc2[0][ni]);
                    acc2[1][ni] = MFMA(a1, bf, acc2[1][ni]);
                }
            }
        }
    }
    // epilogue in two 64-token passes (eL overlays Ts)
    for (int p = 0; p < 2; ++p) {
        __syncthreads();
        if ((wr >> 1) == p) {
            #pragma unroll
            for (int ni = 0; ni < 6; ++ni) {
                const int col = 96 * wc + 16 * ni + c;
                const float b2v = b2[col];
                #pragma unroll
                for (int mi = 0; mi < 2; ++mi)
                    #pragma unroll
                    for (int r = 0; r < 4; ++r) {
                        int tok = 32 * wr + 16 * mi + 4 * g + r;
                        eL[(tok - 64 * p) * 200 + col] =
                            acc2[mi][ni][r] + b2v + bf2f(Xs[tok * 200 + col]);
                    }
            }
        }
        __syncthreads();
        {
            const int tl = tid >> 3, t8 = tid & 7;
            float vals[24], sum = 0.f, ssq = 0.f;
            #pragma unroll
            for (int jv = 0; jv < 6; ++jv) {
                float4 v4 = *(const float4*)&eL[tl * 200 + t8 * 24 + jv * 4];
                vals[jv*4+0] = v4.x; vals[jv*4+1] = v4.y;
                vals[jv*4+2] = v4.z; vals[jv*4+3] = v4.w;
                sum += v4.x + v4.y + v4.z + v4.w;
                ssq += v4.x*v4.x + v4.y*v4.y + v4.z*v4.z + v4.w*v4.w;
            }
            sum += __shfl_xor(sum, 1); sum += __shfl_xor(sum, 2); sum += __shfl_xor(sum, 4);
            ssq += __shfl_xor(ssq, 1); ssq += __shfl_xor(ssq, 2); ssq += __shfl_xor(ssq, 4);
            const float mean = sum * (1.f / D_);
            const float var  = ssq * (1.f / D_) - mean * mean;
            const float rstd = rsqrtf(var + 1e-5f);
            #pragma unroll
            for (int jv = 0; jv < 6; ++jv) {
                us4 o4;
                #pragma unroll
                for (int j = 0; j < 4; ++j) {
                    int col = t8 * 24 + jv * 4 + j;
                    o4[j] = f2bf((vals[jv*4+j] - mean) * rstd * gamma[col] + beta[col]);
                }
                *(us4*)&hio[(size_t)(row0 + 64 * p + tl) * D_ + t8 * 24 + jv * 4] = o4;
            }
        }
    }
}

// ---------------------------------------------------------------------------
// Classifier stage 1 (MFMA): hid = bf16(gelu(h @ Wc1 + bc1)). 64 tok/block.
// ---------------------------------------------------------------------------
__global__ __launch_bounds__(256) void clf1_mfma(
    const us_t* __restrict__ h, const us_t* __restrict__ Wc1t,
    const float* __restrict__ bc1, us_t* __restrict__ hid)
{
    __shared__ __align__(16) char smem[25600 + 13824];
    us_t* Xs = (us_t*)smem;              // [64][200]
    us_t* Ws = (us_t*)(smem + 25600);    // [96][72]
    const int tid = threadIdx.x;
    const int lane = tid & 63, wid = tid >> 6;
    const int g = lane >> 4, c = lane & 15;
    const int wr = wid >> 1, wc = wid & 1;
    const int row0 = blockIdx.x * 64;

    for (int e = tid; e < 1536; e += 256) {
        int tok = e / 24, v = e % 24;
        *(us8*)&Xs[tok * 200 + v * 8] = *(const us8*)&h[(size_t)(row0 + tok) * D_ + v * 8];
    }
    f4 acc[2][3];
    ZACC(acc, 2, 3);
    for (int pc = 0; pc < 3; ++pc) {
        __syncthreads();
        for (int e = tid; e < 768; e += 256) {
            int rw = e >> 3, v = e & 7;
            *(us8*)&Ws[rw * 72 + v * 8] =
                *(const us8*)&Wc1t[(size_t)rw * 192 + pc * 64 + v * 8];
        }
        __syncthreads();
        #pragma unroll
        for (int kk = 0; kk < 2; ++kk) {
            const int ka = pc * 64 + kk * 32 + g * 8;
            const int kw = kk * 32 + g * 8;
            sh8 a0 = *(const sh8*)&Xs[(32 * wr + c) * 200 + ka];
            sh8 a1 = *(const sh8*)&Xs[(32 * wr + 16 + c) * 200 + ka];
            #pragma unroll
            for (int ni = 0; ni < 3; ++ni) {
                sh8 bf = *(const sh8*)&Ws[(48 * wc + 16 * ni + c) * 72 + kw];
                acc[0][ni] = MFMA(a0, bf, acc[0][ni]);
                acc[1][ni] = MFMA(a1, bf, acc[1][ni]);
            }
        }
    }
    #pragma unroll
    for (int ni = 0; ni < 3; ++ni) {
        const int col = 48 * wc + 16 * ni + c;
        const float bv = bc1[col];
        #pragma unroll
        for (int mi = 0; mi < 2; ++mi)
            #pragma unroll
            for (int r = 0; r < 4; ++r) {
                int tok = row0 + 32 * wr + 16 * mi + 4 * g + r;
                hid[(size_t)tok * DH_ + col] = f2bf(gelu_f(acc[mi][ni][r] + bv));
            }
    }
}

// ---------------------------------------------------------------------------
// Classifier stage 2: out = hid @ Wc2 + bc2 (f32 VALU, tiny)
// ---------------------------------------------------------------------------
__global__ __launch_bounds__(256) void clf2_kernel(
    const us_t* __restrict__ hid, const float* __restrict__ Wc2,
    const float* __restrict__ bc2, float* __restrict__ out)
{
    __shared__ us_t Hs[64 * 104];
    __shared__ float Wl[DH_ * NC_];
    __shared__ float bl[NC_];
    const int tid = threadIdx.x;
    const int row0 = blockIdx.x * 64;
    for (int e = tid; e < 768; e += 256) {
        int tok = e / 12, v = e % 12;
        *(us8*)&Hs[tok * 104 + v * 8] = *(const us8*)&hid[(size_t)(row0 + tok) * DH_ + v * 8];
    }
    for (int e = tid; e < DH_ * NC_; e += 256) Wl[e] = Wc2[e];
    if (tid < NC_) bl[tid] = bc2[tid];
    __syncthreads();
    for (int e = tid; e < 64 * NC_; e += 256) {
        const int tok = e / NC_, col = e % NC_;
        float acc = bl[col];
        #pragma unroll 8
        for (int kk = 0; kk < DH_; ++kk)
            acc = fmaf(bf2f(Hs[tok * 104 + kk]), Wl[kk * NC_ + col], acc);
        out[(size_t)(row0 + tok) * NC_ + col] = acc;
    }
}

extern "C" void kernel_launch(void* const* d_in, const int* in_sizes, int n_in,
                              void* d_out, int out_size, void* d_ws, size_t ws_size,
                              hipStream_t stream)
{
    const float* x    = (const float*)d_in[0];
    const float* W_in = (const float*)d_in[1];
    const float* b_in = (const float*)d_in[2];
    const float* pe   = (const float*)d_in[3];
    const float* Wq   = (const float*)d_in[4];
    const float* bq   = (const float*)d_in[5];
    const float* Wk   = (const float*)d_in[6];
    const float* bk   = (const float*)d_in[7];
    const float* Wv   = (const float*)d_in[8];
    const float* bv   = (const float*)d_in[9];
    const float* Wo   = (const float*)d_in[10];
    const float* bo   = (const float*)d_in[11];
    const float* W1   = (const float*)d_in[12];
    const float* b1   = (const float*)d_in[13];
    const float* W2   = (const float*)d_in[14];
    const float* b2   = (const float*)d_in[15];
    const float* g1   = (const float*)d_in[16];
    const float* be1  = (const float*)d_in[17];
    const float* g2   = (const float*)d_in[18];
    const float* be2  = (const float*)d_in[19];
    const float* Wc1  = (const float*)d_in[20];
    const float* bc1  = (const float*)d_in[21];
    const float* Wc2  = (const float*)d_in[22];
    const float* bc2  = (const float*)d_in[23];
    float* outp = (float*)d_out;

    // ws layout (us_t elems): h | hid | bf16 weights
    us_t* h    = (us_t*)d_ws;
    us_t* hid  = h + (size_t)NTOK * D_;
    us_t* Wint = hid + (size_t)NTOK * DH_;
    us_t* Wqt  = Wint + 192 * 224;
    us_t* Wkt  = Wqt + 3 * 36864;
    us_t* Wvt  = Wkt + 3 * 36864;
    us_t* Wot  = Wvt + 3 * 36864;
    us_t* W1t  = Wot + 3 * 36864;
    us_t* W2t  = W1t + 3 * 147456;
    us_t* Wc1t = W2t + 3 * 147456;

    // ---- weight prep ----
    prep_t<<<168, 256, 0, stream>>>(W_in, Wint, IND_, 224, D_);
    for (int l = 0; l < L_; ++l) {
        prep_t<<<144, 256, 0, stream>>>(Wq + (size_t)l * 36864, Wqt + (size_t)l * 36864, 192, 192, 192);
        prep_t<<<144, 256, 0, stream>>>(Wk + (size_t)l * 36864, Wkt + (size_t)l * 36864, 192, 192, 192);
        prep_t<<<144, 256, 0, stream>>>(Wv + (size_t)l * 36864, Wvt + (size_t)l * 36864, 192, 192, 192);
        prep_t<<<144, 256, 0, stream>>>(Wo + (size_t)l * 36864, Wot + (size_t)l * 36864, 192, 192, 192);
        prep_t<<<576, 256, 0, stream>>>(W1 + (size_t)l * 147456, W1t + (size_t)l * 147456, 192, 192, DFF_);
        prep_t<<<576, 256, 0, stream>>>(W2 + (size_t)l * 147456, W2t + (size_t)l * 147456, DFF_, DFF_, 192);
    }
    prep_t<<<72, 256, 0, stream>>>(Wc1, Wc1t, 192, 192, DH_);

    // ---- forward ----
    inp_mfma<<<NTOK / 64, 256, 0, stream>>>(x, Wint, b_in, pe, h);

    for (int l = 0; l < L_; ++l) {
        qkv_attn_wo<<<B_, 512, 0, stream>>>(
            h,
            Wqt + (size_t)l * 36864, Wkt + (size_t)l * 36864,
            Wvt + (size_t)l * 36864, Wot + (size_t)l * 36864,
            bq + l * D_, bk + l * D_, bv + l * D_, bo + l * D_,
            g1 + l * D_, be1 + l * D_);
        ff_mfma<<<NTOK / 128, 512, 0, stream>>>(
            h, W1t + (size_t)l * 147456, b1 + l * DFF_,
            W2t + (size_t)l * 147456, b2 + l * D_,
            g2 + l * D_, be2 + l * D_);
    }

    clf1_mfma<<<NTOK / 64, 256, 0, stream>>>(h, Wc1t, bc1, hid);
    clf2_kernel<<<NTOK / 64, 256, 0, stream>>>(hid, Wc2, bc2, outp);
}

// Round 5
// 1232.571 us; speedup vs baseline: 5.3485x; 1.2284x over previous
//
#include <hip/hip_runtime.h>
#include <cmath>

#define B_   2048
#define S_   60
#define NTOK (B_*S_)
#define IND_ 211
#define D_   192
#define H_   6
#define DK_  32
#define L_   3
#define DFF_ 768
#define NC_  35
#define DH_  96

typedef unsigned short us_t;
typedef us_t us8 __attribute__((ext_vector_type(8)));
typedef us_t us4 __attribute__((ext_vector_type(4)));
typedef short sh8 __attribute__((ext_vector_type(8)));
typedef float f4 __attribute__((ext_vector_type(4)));

#define MFMA(a, b, cc) __builtin_amdgcn_mfma_f32_16x16x32_bf16((a), (b), (cc), 0, 0, 0)
#define ZACC(A, M, N) \
    for (int _i = 0; _i < (M); ++_i) \
        for (int _j = 0; _j < (N); ++_j) { \
            A[_i][_j][0] = 0.f; A[_i][_j][1] = 0.f; A[_i][_j][2] = 0.f; A[_i][_j][3] = 0.f; }
#define ZACC1(A, N) \
    for (int _j = 0; _j < (N); ++_j) { \
        A[_j][0] = 0.f; A[_j][1] = 0.f; A[_j][2] = 0.f; A[_j][3] = 0.f; }

__device__ __forceinline__ float bf2f(us_t u) {
    union { unsigned int i; float f; } v; v.i = ((unsigned int)u) << 16; return v.f;
}
__device__ __forceinline__ us_t f2bf(float f) {
    union { float f; unsigned int i; } v; v.f = f;
    unsigned int r = v.i + 0x7fffu + ((v.i >> 16) & 1u);
    return (us_t)(r >> 16);
}
// fast tanh-gelu: |err| < 1e-3 vs exact erf-gelu, well under bf16 rounding
__device__ __forceinline__ float gelu_f(float v) {
    float u = v * (0.7978845608f + 0.0356774081f * v * v);
    float e = __expf(2.f * u);
    float t = 1.f - 2.f / (e + 1.f);       // overflow-safe tanh
    return 0.5f * v * (1.f + t);
}
__device__ __forceinline__ void gld16(const us_t* g, us_t* s) {
    __builtin_amdgcn_global_load_lds(
        (const __attribute__((address_space(1))) unsigned int*)(g),
        (__attribute__((address_space(3))) unsigned int*)(s), 16, 0, 0);
}

// ---------------------------------------------------------------------------
// Weight prep (qkv/wo/inp/clf1): out[n][kp] = bf16(in[kp][n]), zero-pad Kpad.
// ---------------------------------------------------------------------------
__global__ void prep_t(const float* __restrict__ in, us_t* __restrict__ out,
                       int K, int Kpad, int N)
{
    int e = blockIdx.x * 256 + threadIdx.x;
    if (e >= N * Kpad) return;
    int n = e / Kpad, kp = e % Kpad;
    out[e] = (kp < K) ? f2bf(in[(size_t)kp * N + n]) : (us_t)0;
}

// ---------------------------------------------------------------------------
// FF weight prep: tile-contiguous LDS images. Per layer 12 tiles x [192][72].
// W1 tile (cb,pc): col=out-col cb*192+c, k=pc*64+kk (K=192). W2: K=768.
// ---------------------------------------------------------------------------
__global__ void prep_ff(const float* __restrict__ W1, const float* __restrict__ W2,
                        us_t* __restrict__ W1T, us_t* __restrict__ W2T)
{
    int e = blockIdx.x * 256 + threadIdx.x;
    if (e >= L_ * 12 * 13824) return;
    int l = e / (12 * 13824), r = e % (12 * 13824);
    int tile = r / 13824, q = r % 13824;
    int col = q / 72, kk = q % 72;
    int cb = tile / 3, pc = tile % 3;
    us_t v1 = 0, v2 = 0;
    if (kk < 64) {
        v1 = f2bf(W1[((size_t)l * D_ + pc * 64 + kk) * DFF_ + cb * D_ + col]);
        v2 = f2bf(W2[((size_t)l * DFF_ + cb * D_ + pc * 64 + kk) * D_ + col]);
    }
    W1T[e] = v1; W2T[e] = v2;
}

// ---------------------------------------------------------------------------
// Input projection: h = bf16(x @ W_in + b_in + pe). 64 tok/block, 4 waves.
// ---------------------------------------------------------------------------
__global__ __launch_bounds__(256) void inp_mfma(
    const float* __restrict__ x, const us_t* __restrict__ Wint,
    const float* __restrict__ b_in, const float* __restrict__ pe,
    us_t* __restrict__ h)
{
    __shared__ __align__(16) char smem[29696 + 27648];
    us_t* Xs = (us_t*)smem;              // [64][232]
    us_t* Ws = (us_t*)(smem + 29696);    // [192][72]
    const int tid = threadIdx.x;
    const int lane = tid & 63, wid = tid >> 6;
    const int g = lane >> 4, c = lane & 15;
    const int wr = wid >> 1, wc = wid & 1;
    const int row0 = blockIdx.x * 64;

    for (int e = tid; e < 64 * 224; e += 256) {
        int tok = e / 224, kp = e % 224;
        float v = (kp < IND_) ? x[(size_t)(row0 + tok) * IND_ + kp] : 0.f;
        Xs[tok * 232 + kp] = f2bf(v);
    }

    f4 acc[2][6];
    ZACC(acc, 2, 6);
    for (int pc = 0; pc < 4; ++pc) {
        __syncthreads();
        const int nk = (pc < 3) ? 64 : 32;
        const int per = nk / 8;
        for (int e = tid; e < 192 * per; e += 256) {
            int rw = e / per, v = e % per;
            *(us8*)&Ws[rw * 72 + v * 8] =
                *(const us8*)&Wint[(size_t)rw * 224 + pc * 64 + v * 8];
        }
        __syncthreads();
        for (int kk = 0; kk < nk / 32; ++kk) {
            const int ka = pc * 64 + kk * 32 + g * 8;
            const int kw = kk * 32 + g * 8;
            sh8 a0 = *(const sh8*)&Xs[(32 * wr + c) * 232 + ka];
            sh8 a1 = *(const sh8*)&Xs[(32 * wr + 16 + c) * 232 + ka];
            #pragma unroll
            for (int ni = 0; ni < 6; ++ni) {
                sh8 bf = *(const sh8*)&Ws[(96 * wc + 16 * ni + c) * 72 + kw];
                acc[0][ni] = MFMA(a0, bf, acc[0][ni]);
                acc[1][ni] = MFMA(a1, bf, acc[1][ni]);
            }
        }
    }
    #pragma unroll
    for (int ni = 0; ni < 6; ++ni) {
        const int col = 96 * wc + 16 * ni + c;
        const float bv = b_in[col];
        #pragma unroll
        for (int mi = 0; mi < 2; ++mi)
            #pragma unroll
            for (int r = 0; r < 4; ++r) {
                int tokg = row0 + 32 * wr + 16 * mi + 4 * g + r;
                int s = tokg % S_;
                float val = acc[mi][ni][r] + bv + pe[(size_t)s * D_ + col];
                h[(size_t)tokg * D_ + col] = f2bf(val);
            }
    }
}

// ---------------------------------------------------------------------------
// Fused QKV + attention + Wo + residual + LN. One 512-thread block per batch.
// ---------------------------------------------------------------------------
__global__ __launch_bounds__(512) void qkv_attn_wo(
    us_t* __restrict__ h,
    const us_t* __restrict__ Wqt, const us_t* __restrict__ Wkt,
    const us_t* __restrict__ Wvt, const us_t* __restrict__ Wot,
    const float* __restrict__ bq, const float* __restrict__ bk,
    const float* __restrict__ bv, const float* __restrict__ bo,
    const float* __restrict__ g1, const float* __restrict__ be1)
{
    __shared__ __align__(16) char smem[157696];
    us_t* Xs = (us_t*)smem;               // [64][200]
    us_t* Qs = (us_t*)(smem + 25600);     // [64][200]
    us_t* Ks = (us_t*)(smem + 51200);     // [64][200]
    us_t* Vt = (us_t*)(smem + 76800);     // [192][72] (V transposed)
    us_t* Ws = (us_t*)(smem + 104448);    // [192][72]
    us_t* P0 = (us_t*)(smem + 104448);    // [64][72] overlays Ws
    us_t* P1 = (us_t*)(smem + 113664);    // [64][72]
    us_t* Cx = (us_t*)(smem + 132096);    // [64][200]
    float* eL = (float*)(smem + 51200);   // [64][200] f32 overlays Ks+Vt

    const int tid = threadIdx.x;
    const int lane = tid & 63, wid = tid >> 6;
    const int g = lane >> 4, c = lane & 15;
    const int wr = wid >> 2, wc = wid & 3;
    us_t* hb = h + (size_t)blockIdx.x * (S_ * D_);

    for (int e = tid; e < 1536; e += 512) {
        int tok = e / 24, v = e % 24;
        us8 u = {0, 0, 0, 0, 0, 0, 0, 0};
        if (tok < S_) u = *(const us8*)&hb[(size_t)tok * D_ + v * 8];
        *(us8*)&Xs[tok * 200 + v * 8] = u;
    }

    for (int m = 0; m < 3; ++m) {
        const us_t* Wt = (m == 0) ? Wqt : (m == 1) ? Wkt : Wvt;
        const float* bb = (m == 0) ? bq : (m == 1) ? bk : bv;
        f4 acc[2][3];
        ZACC(acc, 2, 3);
        for (int pc = 0; pc < 3; ++pc) {
            __syncthreads();
            for (int e = tid; e < 1536; e += 512) {
                int rw = e >> 3, v = e & 7;
                *(us8*)&Ws[rw * 72 + v * 8] =
                    *(const us8*)&Wt[(size_t)rw * 192 + pc * 64 + v * 8];
            }
            __syncthreads();
            #pragma unroll
            for (int kk = 0; kk < 2; ++kk) {
                const int ka = pc * 64 + kk * 32 + g * 8;
                const int kw = kk * 32 + g * 8;
                sh8 a0 = *(const sh8*)&Xs[(32 * wr + c) * 200 + ka];
                sh8 a1 = *(const sh8*)&Xs[(32 * wr + 16 + c) * 200 + ka];
                #pragma unroll
                for (int ni = 0; ni < 3; ++ni) {
                    sh8 bf = *(const sh8*)&Ws[(48 * wc + 16 * ni + c) * 72 + kw];
                    acc[0][ni] = MFMA(a0, bf, acc[0][ni]);
                    acc[1][ni] = MFMA(a1, bf, acc[1][ni]);
                }
            }
        }
        #pragma unroll
        for (int ni = 0; ni < 3; ++ni) {
            const int col = 48 * wc + 16 * ni + c;
            const float bval = bb[col];
            #pragma unroll
            for (int mi = 0; mi < 2; ++mi)
                #pragma unroll
                for (int r = 0; r < 4; ++r) {
                    int tok = 32 * wr + 16 * mi + 4 * g + r;
                    us_t o = f2bf(acc[mi][ni][r] + bval);
                    if (m == 0)      Qs[tok * 200 + col] = o;
                    else if (m == 1) Ks[tok * 200 + col] = o;
                    else             Vt[col * 72 + tok] = o;
                }
        }
    }
    __syncthreads();

    const int hgrp = wid & 3;
    const int hsel = wid >> 2;
    for (int rr = 0; rr < 3; ++rr) {
        const int hh = 2 * rr + hsel;
        us_t* Pb = hsel ? P1 : P0;
        f4 sc[4];
        ZACC1(sc, 4);
        {
            const int ka = 32 * hh + g * 8;
            sh8 aq = *(const sh8*)&Qs[(16 * hgrp + c) * 200 + ka];
            #pragma unroll
            for (int ni = 0; ni < 4; ++ni) {
                sh8 bk8 = *(const sh8*)&Ks[(16 * ni + c) * 200 + ka];
                sc[ni] = MFMA(aq, bk8, sc[ni]);
            }
        }
        #pragma unroll
        for (int r = 0; r < 4; ++r) {
            float mx = -1e30f;
            #pragma unroll
            for (int ni = 0; ni < 4; ++ni) {
                float v = sc[ni][r] * 0.17677669529663687f;
                if (16 * ni + c >= S_) v = -1e30f;
                sc[ni][r] = v;
                mx = fmaxf(mx, v);
            }
            mx = fmaxf(mx, __shfl_xor(mx, 1));
            mx = fmaxf(mx, __shfl_xor(mx, 2));
            mx = fmaxf(mx, __shfl_xor(mx, 4));
            mx = fmaxf(mx, __shfl_xor(mx, 8));
            float sum = 0.f;
            #pragma unroll
            for (int ni = 0; ni < 4; ++ni) {
                float e = __expf(sc[ni][r] - mx);
                sc[ni][r] = e; sum += e;
            }
            sum += __shfl_xor(sum, 1);
            sum += __shfl_xor(sum, 2);
            sum += __shfl_xor(sum, 4);
            sum += __shfl_xor(sum, 8);
            const float inv = 1.f / sum;
            #pragma unroll
            for (int ni = 0; ni < 4; ++ni)
                Pb[(16 * hgrp + 4 * g + r) * 72 + 16 * ni + c] = f2bf(sc[ni][r] * inv);
        }
        __syncthreads();
        f4 ov[2];
        ZACC1(ov, 2);
        #pragma unroll
        for (int kk = 0; kk < 2; ++kk) {
            sh8 ap = *(const sh8*)&Pb[(16 * hgrp + c) * 72 + kk * 32 + g * 8];
            #pragma unroll
            for (int n2 = 0; n2 < 2; ++n2) {
                sh8 bv8 = *(const sh8*)&Vt[(32 * hh + 16 * n2 + c) * 72 + kk * 32 + g * 8];
                ov[n2] = MFMA(ap, bv8, ov[n2]);
            }
        }
        #pragma unroll
        for (int n2 = 0; n2 < 2; ++n2)
            #pragma unroll
            for (int r = 0; r < 4; ++r)
                Cx[(16 * hgrp + 4 * g + r) * 200 + 32 * hh + 16 * n2 + c] = f2bf(ov[n2][r]);
        __syncthreads();
    }

    f4 aw[2][3];
    ZACC(aw, 2, 3);
    for (int pc = 0; pc < 3; ++pc) {
        __syncthreads();
        for (int e = tid; e < 1536; e += 512) {
            int rw = e >> 3, v = e & 7;
            *(us8*)&Ws[rw * 72 + v * 8] =
                *(const us8*)&Wot[(size_t)rw * 192 + pc * 64 + v * 8];
        }
        __syncthreads();
        #pragma unroll
        for (int kk = 0; kk < 2; ++kk) {
            const int ka = pc * 64 + kk * 32 + g * 8;
            const int kw = kk * 32 + g * 8;
            sh8 a0 = *(const sh8*)&Cx[(32 * wr + c) * 200 + ka];
            sh8 a1 = *(const sh8*)&Cx[(32 * wr + 16 + c) * 200 + ka];
            #pragma unroll
            for (int ni = 0; ni < 3; ++ni) {
                sh8 bf = *(const sh8*)&Ws[(48 * wc + 16 * ni + c) * 72 + kw];
                aw[0][ni] = MFMA(a0, bf, aw[0][ni]);
                aw[1][ni] = MFMA(a1, bf, aw[1][ni]);
            }
        }
    }
    __syncthreads();
    #pragma unroll
    for (int ni = 0; ni < 3; ++ni) {
        const int col = 48 * wc + 16 * ni + c;
        const float bov = bo[col];
        #pragma unroll
        for (int mi = 0; mi < 2; ++mi)
            #pragma unroll
            for (int r = 0; r < 4; ++r) {
                int tok = 32 * wr + 16 * mi + 4 * g + r;
                eL[tok * 200 + col] = aw[mi][ni][r] + bov + bf2f(Xs[tok * 200 + col]);
            }
    }
    __syncthreads();
    {
        const int tok = tid >> 3, t8 = tid & 7;
        float vals[24], sum = 0.f, ssq = 0.f;
        #pragma unroll
        for (int jv = 0; jv < 6; ++jv) {
            float4 v4 = *(const float4*)&eL[tok * 200 + t8 * 24 + jv * 4];
            vals[jv*4+0] = v4.x; vals[jv*4+1] = v4.y; vals[jv*4+2] = v4.z; vals[jv*4+3] = v4.w;
            sum += v4.x + v4.y + v4.z + v4.w;
            ssq += v4.x*v4.x + v4.y*v4.y + v4.z*v4.z + v4.w*v4.w;
        }
        sum += __shfl_xor(sum, 1); sum += __shfl_xor(sum, 2); sum += __shfl_xor(sum, 4);
        ssq += __shfl_xor(ssq, 1); ssq += __shfl_xor(ssq, 2); ssq += __shfl_xor(ssq, 4);
        const float mean = sum * (1.f / D_);
        const float var  = ssq * (1.f / D_) - mean * mean;
        const float rstd = rsqrtf(var + 1e-5f);
        if (tok < S_) {
            #pragma unroll
            for (int jv = 0; jv < 6; ++jv) {
                us4 o4;
                #pragma unroll
                for (int j = 0; j < 4; ++j) {
                    int col = t8 * 24 + jv * 4 + j;
                    o4[j] = f2bf((vals[jv*4+j] - mean) * rstd * g1[col] + be1[col]);
                }
                *(us4*)&hb[(size_t)tok * D_ + t8 * 24 + jv * 4] = o4;
            }
        }
    }
}

// ---------------------------------------------------------------------------
// Fused FF (pipelined): gelu(x@W1+b1)@W2+b2 + resid + LN. 128 tok, 8 waves.
// Weight tiles (exact LDS images) double-buffered via global_load_lds;
// one barrier per tile; next-tile loads in flight during MFMA.
// ---------------------------------------------------------------------------
__device__ __forceinline__ void ff_tile(const us_t* A, f4 (&acc)[2][6],
                                        const us_t* W, int pc,
                                        int wr, int wc, int g, int c)
{
    #pragma unroll
    for (int kk = 0; kk < 2; ++kk) {
        const int ka = pc * 64 + kk * 32 + g * 8;
        const int kw = kk * 32 + g * 8;
        sh8 a0 = *(const sh8*)&A[(32 * wr + c) * 200 + ka];
        sh8 a1 = *(const sh8*)&A[(32 * wr + 16 + c) * 200 + ka];
        #pragma unroll
        for (int ni = 0; ni < 6; ++ni) {
            sh8 bf = *(const sh8*)&W[(96 * wc + 16 * ni + c) * 72 + kw];
            acc[0][ni] = MFMA(a0, bf, acc[0][ni]);
            acc[1][ni] = MFMA(a1, bf, acc[1][ni]);
        }
    }
}

__global__ __launch_bounds__(512) void ff_mfma(
    us_t* __restrict__ hio,
    const us_t* __restrict__ W1T, const float* __restrict__ b1,
    const us_t* __restrict__ W2T, const float* __restrict__ b2,
    const float* __restrict__ gamma, const float* __restrict__ beta)
{
    __shared__ __align__(16) char smem[157696];
    us_t* Xs  = (us_t*)smem;               // [128][200]
    us_t* Ts  = (us_t*)(smem + 51200);     // [128][200]
    us_t* Wsb = (us_t*)(smem + 102400);    // [2][192][72] dbuf tiles
    float* eL = (float*)(smem + 51200);    // overlays Ts (epilogue)

    const int tid = threadIdx.x;
    const int lane = tid & 63, wid = tid >> 6;
    const int g = lane >> 4, c = lane & 15;
    const int wr = wid >> 1, wc = wid & 1;
    const int row0 = blockIdx.x * 128;

    // tile t = cb*6 + ph*3 + pc; src image 13824 us_t each
    auto stageW = [&](int t) {
        const int cb2 = t / 6, ph = (t % 6) / 3, pc2 = t % 3;
        const us_t* src = (ph ? W2T : W1T) + (size_t)(cb2 * 3 + pc2) * 13824;
        us_t* dst = Wsb + (size_t)(t & 1) * 13824;
        #pragma unroll
        for (int i = wid; i < 27; i += 8)
            gld16(src + i * 512 + lane * 8, dst + i * 512);
    };

    // stage X + first weight tile
    for (int e = tid; e < 3072; e += 512) {
        int tok = e / 24, v = e % 24;
        *(us8*)&Xs[tok * 200 + v * 8] = *(const us8*)&hio[(size_t)(row0 + tok) * D_ + v * 8];
    }
    stageW(0);
    __syncthreads();

    f4 acc2[2][6];
    ZACC(acc2, 2, 6);
    for (int cb = 0; cb < 4; ++cb) {
        f4 acc1[2][6];
        ZACC(acc1, 2, 6);
        #pragma unroll
        for (int pc = 0; pc < 3; ++pc) {            // FF1
            const int t = cb * 6 + pc;
            if (t < 23) stageW(t + 1);
            ff_tile(Xs, acc1, Wsb + (size_t)(t & 1) * 13824, pc, wr, wc, g, c);
            if (pc == 2) {
                #pragma unroll
                for (int ni = 0; ni < 6; ++ni) {
                    const int col = 96 * wc + 16 * ni + c;
                    const float b1v = b1[cb * 192 + col];
                    #pragma unroll
                    for (int mi = 0; mi < 2; ++mi)
                        #pragma unroll
                        for (int r = 0; r < 4; ++r) {
                            int tok = 32 * wr + 16 * mi + 4 * g + r;
                            Ts[tok * 200 + col] = f2bf(gelu_f(acc1[mi][ni][r] + b1v));
                        }
                }
            }
            __syncthreads();
        }
        #pragma unroll
        for (int pc = 0; pc < 3; ++pc) {            // FF2 partial
            const int t = cb * 6 + 3 + pc;
            if (t < 23) stageW(t + 1);
            ff_tile(Ts, acc2, Wsb + (size_t)(t & 1) * 13824, pc, wr, wc, g, c);
            __syncthreads();
        }
    }

    // epilogue in two 64-token passes (eL overlays Ts)
    for (int p = 0; p < 2; ++p) {
        if (p) __syncthreads();
        if ((wr >> 1) == p) {
            #pragma unroll
            for (int ni = 0; ni < 6; ++ni) {
                const int col = 96 * wc + 16 * ni + c;
                const float b2v = b2[col];
                #pragma unroll
                for (int mi = 0; mi < 2; ++mi)
                    #pragma unroll
                    for (int r = 0; r < 4; ++r) {
                        int tok = 32 * wr + 16 * mi + 4 * g + r;
                        eL[(tok - 64 * p) * 200 + col] =
                            acc2[mi][ni][r] + b2v + bf2f(Xs[tok * 200 + col]);
                    }
            }
        }
        __syncthreads();
        {
            const int tl = tid >> 3, t8 = tid & 7;
            float vals[24], sum = 0.f, ssq = 0.f;
            #pragma unroll
            for (int jv = 0; jv < 6; ++jv) {
                float4 v4 = *(const float4*)&eL[tl * 200 + t8 * 24 + jv * 4];
                vals[jv*4+0] = v4.x; vals[jv*4+1] = v4.y;
                vals[jv*4+2] = v4.z; vals[jv*4+3] = v4.w;
                sum += v4.x + v4.y + v4.z + v4.w;
                ssq += v4.x*v4.x + v4.y*v4.y + v4.z*v4.z + v4.w*v4.w;
            }
            sum += __shfl_xor(sum, 1); sum += __shfl_xor(sum, 2); sum += __shfl_xor(sum, 4);
            ssq += __shfl_xor(ssq, 1); ssq += __shfl_xor(ssq, 2); ssq += __shfl_xor(ssq, 4);
            const float mean = sum * (1.f / D_);
            const float var  = ssq * (1.f / D_) - mean * mean;
            const float rstd = rsqrtf(var + 1e-5f);
            #pragma unroll
            for (int jv = 0; jv < 6; ++jv) {
                us4 o4;
                #pragma unroll
                for (int j = 0; j < 4; ++j) {
                    int col = t8 * 24 + jv * 4 + j;
                    o4[j] = f2bf((vals[jv*4+j] - mean) * rstd * gamma[col] + beta[col]);
                }
                *(us4*)&hio[(size_t)(row0 + 64 * p + tl) * D_ + t8 * 24 + jv * 4] = o4;
            }
        }
    }
}

// ---------------------------------------------------------------------------
// Classifier stage 1 (MFMA): hid = bf16(gelu(h @ Wc1 + bc1)). 64 tok/block.
// ---------------------------------------------------------------------------
__global__ __launch_bounds__(256) void clf1_mfma(
    const us_t* __restrict__ h, const us_t* __restrict__ Wc1t,
    const float* __restrict__ bc1, us_t* __restrict__ hid)
{
    __shared__ __align__(16) char smem[25600 + 13824];
    us_t* Xs = (us_t*)smem;              // [64][200]
    us_t* Ws = (us_t*)(smem + 25600);    // [96][72]
    const int tid = threadIdx.x;
    const int lane = tid & 63, wid = tid >> 6;
    const int g = lane >> 4, c = lane & 15;
    const int wr = wid >> 1, wc = wid & 1;
    const int row0 = blockIdx.x * 64;

    for (int e = tid; e < 1536; e += 256) {
        int tok = e / 24, v = e % 24;
        *(us8*)&Xs[tok * 200 + v * 8] = *(const us8*)&h[(size_t)(row0 + tok) * D_ + v * 8];
    }
    f4 acc[2][3];
    ZACC(acc, 2, 3);
    for (int pc = 0; pc < 3; ++pc) {
        __syncthreads();
        for (int e = tid; e < 768; e += 256) {
            int rw = e >> 3, v = e & 7;
            *(us8*)&Ws[rw * 72 + v * 8] =
                *(const us8*)&Wc1t[(size_t)rw * 192 + pc * 64 + v * 8];
        }
        __syncthreads();
        #pragma unroll
        for (int kk = 0; kk < 2; ++kk) {
            const int ka = pc * 64 + kk * 32 + g * 8;
            const int kw = kk * 32 + g * 8;
            sh8 a0 = *(const sh8*)&Xs[(32 * wr + c) * 200 + ka];
            sh8 a1 = *(const sh8*)&Xs[(32 * wr + 16 + c) * 200 + ka];
            #pragma unroll
            for (int ni = 0; ni < 3; ++ni) {
                sh8 bf = *(const sh8*)&Ws[(48 * wc + 16 * ni + c) * 72 + kw];
                acc[0][ni] = MFMA(a0, bf, acc[0][ni]);
                acc[1][ni] = MFMA(a1, bf, acc[1][ni]);
            }
        }
    }
    #pragma unroll
    for (int ni = 0; ni < 3; ++ni) {
        const int col = 48 * wc + 16 * ni + c;
        const float bv = bc1[col];
        #pragma unroll
        for (int mi = 0; mi < 2; ++mi)
            #pragma unroll
            for (int r = 0; r < 4; ++r) {
                int tok = row0 + 32 * wr + 16 * mi + 4 * g + r;
                hid[(size_t)tok * DH_ + col] = f2bf(gelu_f(acc[mi][ni][r] + bv));
            }
    }
}

// ---------------------------------------------------------------------------
// Classifier stage 2: out = hid @ Wc2 + bc2 (f32 VALU, tiny)
// ---------------------------------------------------------------------------
__global__ __launch_bounds__(256) void clf2_kernel(
    const us_t* __restrict__ hid, const float* __restrict__ Wc2,
    const float* __restrict__ bc2, float* __restrict__ out)
{
    __shared__ us_t Hs[64 * 104];
    __shared__ float Wl[DH_ * NC_];
    __shared__ float bl[NC_];
    const int tid = threadIdx.x;
    const int row0 = blockIdx.x * 64;
    for (int e = tid; e < 768; e += 256) {
        int tok = e / 12, v = e % 12;
        *(us8*)&Hs[tok * 104 + v * 8] = *(const us8*)&hid[(size_t)(row0 + tok) * DH_ + v * 8];
    }
    for (int e = tid; e < DH_ * NC_; e += 256) Wl[e] = Wc2[e];
    if (tid < NC_) bl[tid] = bc2[tid];
    __syncthreads();
    for (int e = tid; e < 64 * NC_; e += 256) {
        const int tok = e / NC_, col = e % NC_;
        float acc = bl[col];
        #pragma unroll 8
        for (int kk = 0; kk < DH_; ++kk)
            acc = fmaf(bf2f(Hs[tok * 104 + kk]), Wl[kk * NC_ + col], acc);
        out[(size_t)(row0 + tok) * NC_ + col] = acc;
    }
}

extern "C" void kernel_launch(void* const* d_in, const int* in_sizes, int n_in,
                              void* d_out, int out_size, void* d_ws, size_t ws_size,
                              hipStream_t stream)
{
    const float* x    = (const float*)d_in[0];
    const float* W_in = (const float*)d_in[1];
    const float* b_in = (const float*)d_in[2];
    const float* pe   = (const float*)d_in[3];
    const float* Wq   = (const float*)d_in[4];
    const float* bq   = (const float*)d_in[5];
    const float* Wk   = (const float*)d_in[6];
    const float* bk   = (const float*)d_in[7];
    const float* Wv   = (const float*)d_in[8];
    const float* bv   = (const float*)d_in[9];
    const float* Wo   = (const float*)d_in[10];
    const float* bo   = (const float*)d_in[11];
    const float* W1   = (const float*)d_in[12];
    const float* b1   = (const float*)d_in[13];
    const float* W2   = (const float*)d_in[14];
    const float* b2   = (const float*)d_in[15];
    const float* g1   = (const float*)d_in[16];
    const float* be1  = (const float*)d_in[17];
    const float* g2   = (const float*)d_in[18];
    const float* be2  = (const float*)d_in[19];
    const float* Wc1  = (const float*)d_in[20];
    const float* bc1  = (const float*)d_in[21];
    const float* Wc2  = (const float*)d_in[22];
    const float* bc2  = (const float*)d_in[23];
    float* outp = (float*)d_out;

    // ws layout (us_t elems): h | hid | Wint | Wq/k/v/ot | W1T | W2T | Wc1t
    us_t* h    = (us_t*)d_ws;
    us_t* hid  = h + (size_t)NTOK * D_;
    us_t* Wint = hid + (size_t)NTOK * DH_;
    us_t* Wqt  = Wint + 192 * 224;
    us_t* Wkt  = Wqt + 3 * 36864;
    us_t* Wvt  = Wkt + 3 * 36864;
    us_t* Wot  = Wvt + 3 * 36864;
    us_t* W1T  = Wot + 3 * 36864;
    us_t* W2T  = W1T + (size_t)L_ * 12 * 13824;
    us_t* Wc1t = W2T + (size_t)L_ * 12 * 13824;

    // ---- weight prep ----
    prep_t<<<168, 256, 0, stream>>>(W_in, Wint, IND_, 224, D_);
    for (int l = 0; l < L_; ++l) {
        prep_t<<<144, 256, 0, stream>>>(Wq + (size_t)l * 36864, Wqt + (size_t)l * 36864, 192, 192, 192);
        prep_t<<<144, 256, 0, stream>>>(Wk + (size_t)l * 36864, Wkt + (size_t)l * 36864, 192, 192, 192);
        prep_t<<<144, 256, 0, stream>>>(Wv + (size_t)l * 36864, Wvt + (size_t)l * 36864, 192, 192, 192);
        prep_t<<<144, 256, 0, stream>>>(Wo + (size_t)l * 36864, Wot + (size_t)l * 36864, 192, 192, 192);
    }
    prep_ff<<<(L_ * 12 * 13824 + 255) / 256, 256, 0, stream>>>(W1, W2, W1T, W2T);
    prep_t<<<72, 256, 0, stream>>>(Wc1, Wc1t, 192, 192, DH_);

    // ---- forward ----
    inp_mfma<<<NTOK / 64, 256, 0, stream>>>(x, Wint, b_in, pe, h);

    for (int l = 0; l < L_; ++l) {
        qkv_attn_wo<<<B_, 512, 0, stream>>>(
            h,
            Wqt + (size_t)l * 36864, Wkt + (size_t)l * 36864,
            Wvt + (size_t)l * 36864, Wot + (size_t)l * 36864,
            bq + l * D_, bk + l * D_, bv + l * D_, bo + l * D_,
            g1 + l * D_, be1 + l * D_);
        ff_mfma<<<NTOK / 128, 512, 0, stream>>>(
            h, W1T + (size_t)l * 12 * 13824, b1 + l * DFF_,
            W2T + (size_t)l * 12 * 13824, b2 + l * D_,
            g2 + l * D_, be2 + l * D_);
    }

    clf1_mfma<<<NTOK / 64, 256, 0, stream>>>(h, Wc1t, bc1, hid);
    clf2_kernel<<<NTOK / 64, 256, 0, stream>>>(hid, Wc2, bc2, outp);
}